// Round 6
// baseline (636.086 us; speedup 1.0000x reference)
//
#include <hip/hip_runtime.h>
#include <math.h>

#define IMSZ 28
#define PSZ  8
#define LAMF 0.001f
#define NREP 8          // coact replica buffers (atomic spread)
#define NPAIR 120       // symmetric upper-triangle pairs of 15x15
#define CSTR 128        // floats per replica slot (120 used)

// Sample-per-thread, zero LDS on the hot path: all weights / R / mask /
// coact read via wave-uniform compile-time-offset loads -> scalar cache
// (s_load), VALU consumes SGPR operands directly. DS pipe is used only for
// the per-block coact outer-product reduction (120 symmetric pairs, exact
// since s_i*s_j commutes). Patch row = 3 aligned dwordx4 (d=pc&3 is
// row-invariant: 28 % 4 == 0); FIRST step folds the funnel at compile time.
template<bool FIRST, bool LAST>
__global__ __launch_bounds__(256, 1) void step_spt(
    const float* __restrict__ x,
    const float* __restrict__ Wi, const float* __restrict__ bi,
    const float* __restrict__ gamma, const float* __restrict__ beta,
    const float* __restrict__ R, const float* __restrict__ rb,
    const float* __restrict__ mask,
    const float* __restrict__ Wc, const float* __restrict__ bc,
    const float* __restrict__ Wo, const float* __restrict__ bo,
    float* __restrict__ state, int* __restrict__ pos,
    const float* __restrict__ coact_in, float* __restrict__ coact_out,
    float* __restrict__ out, int B, float lamB)
{
    __shared__ float sS[256 * 16];

    const int tid = threadIdx.x;
    const int b = blockIdx.x * 256 + tid;
    const float* img = x + (size_t)b * (IMSZ * IMSZ);

    int pr, pc;
    if (FIRST) { pr = 10; pc = 10; }
    else { int p = pos[b]; pr = p >> 8; pc = p & 255; }

    // ---- patch gather: per row 3 aligned dwordx4 (+ funnel when pc varies) ----
    float patch[64];
    {
        const int base = pr * IMSZ + pc;        // float index of row-0 start
        const int a0 = base & ~3;               // 16B-aligned float index
        if (FIRST) {
            // pc==10, pr==10 -> base=290, d=2 -> patch = f[2..9]
#pragma unroll
            for (int r = 0; r < 8; ++r) {
                const float4* q = (const float4*)(img + a0 + r * IMSZ);
                float4 q0 = q[0], q1 = q[1], q2 = q[2];
                patch[r * 8 + 0] = q0.z; patch[r * 8 + 1] = q0.w;
                patch[r * 8 + 2] = q1.x; patch[r * 8 + 3] = q1.y;
                patch[r * 8 + 4] = q1.z; patch[r * 8 + 5] = q1.w;
                patch[r * 8 + 6] = q2.x; patch[r * 8 + 7] = q2.y;
            }
        } else {
            const int d = base & 3;
            const bool s2 = (d & 2) != 0, s1 = (d & 1) != 0;
#pragma unroll
            for (int r = 0; r < 8; ++r) {
                const float4* q = (const float4*)(img + a0 + r * IMSZ);
                float4 q0 = q[0], q1 = q[1], q2 = q[2];
                const float f[12] = { q0.x, q0.y, q0.z, q0.w,
                                      q1.x, q1.y, q1.z, q1.w,
                                      q2.x, q2.y, q2.z, q2.w };
                float t[9];
#pragma unroll
                for (int c = 0; c < 9; ++c) t[c] = s2 ? f[c + 2] : f[c];
#pragma unroll
                for (int c = 0; c < 8; ++c) patch[r * 8 + c] = s1 ? t[c + 1] : t[c];
            }
        }
    }

    const float posr = ((float)pr / 20.0f) * 2.0f - 1.0f;
    const float posc = ((float)pc / 20.0f) * 2.0f - 1.0f;

    // ---- input matvec: weights via scalar cache (wave-uniform offsets) ----
    float h[15];
#pragma unroll
    for (int u = 0; u < 15; ++u) {
        const float* w = Wi + u * 66;
        float a = 0.0f;
#pragma unroll
        for (int k = 0; k < 64; ++k) a = fmaf(patch[k], w[k], a);
        a = fmaf(posr, w[64], a);
        a = fmaf(posc, w[65], a);
        h[u] = a + bi[u];
    }

    // ---- recurrent term with inline Reff = (R - lam/B * coact) * mask ----
    if (!FIRST) {
        float sprev[15];
#pragma unroll
        for (int j = 0; j < 15; ++j) sprev[j] = state[(size_t)j * B + b];
#pragma unroll
        for (int j = 0; j < 15; ++j) {
            const float sj = sprev[j];
#pragma unroll
            for (int u = 0; u < 15; ++u) {
                const int i0 = u < j ? u : j;
                const int j0 = u < j ? j : u;
                const int sid = i0 * 15 + j0 - (i0 * (i0 + 1)) / 2;
                float cs = 0.0f;
#pragma unroll
                for (int rr = 0; rr < NREP; ++rr) cs += coact_in[rr * CSTR + sid];
                const float reff = (R[u * 15 + j] - lamB * cs) * mask[u * 15 + j];
                h[u] = fmaf(sj, reff, h[u]);
            }
        }
#pragma unroll
        for (int u = 0; u < 15; ++u) h[u] += rb[u];
    }

    // ---- relu + LayerNorm ----
#pragma unroll
    for (int u = 0; u < 15; ++u) h[u] = fmaxf(h[u], 0.0f);
    float mu = 0.0f;
#pragma unroll
    for (int u = 0; u < 15; ++u) mu += h[u];
    mu *= (1.0f / 15.0f);
    float var = 0.0f;
#pragma unroll
    for (int u = 0; u < 15; ++u) { float dd = h[u] - mu; var = fmaf(dd, dd, var); }
    var *= (1.0f / 15.0f);
    const float rs = 1.0f / sqrtf(var + 1e-5f);
    float st[15];
#pragma unroll
    for (int u = 0; u < 15; ++u) st[u] = (h[u] - mu) * rs * gamma[u] + beta[u];

    if (LAST) {
#pragma unroll
        for (int o = 0; o < 10; ++o) {
            float a = 0.0f;
#pragma unroll
            for (int j = 0; j < 15; ++j) a = fmaf(st[j], Wo[o * 15 + j], a);
            out[(size_t)b * 10 + o] = a + bo[o];
        }
    } else {
        // ---- persist state (SoA, coalesced) ----
#pragma unroll
        for (int j = 0; j < 15; ++j) state[(size_t)j * B + b] = st[j];

        // ---- control head / position update ----
        float c0 = 0.0f, c1 = 0.0f;
#pragma unroll
        for (int j = 0; j < 15; ++j) {
            c0 = fmaf(st[j], Wc[j], c0);
            c1 = fmaf(st[j], Wc[15 + j], c1);
        }
        c0 = tanhf(c0 + bc[0]);
        c1 = tanhf(c1 + bc[1]);
        const float m0 = fabsf(c0), m1 = fabsf(c1);
        int rm, cm;
        if (m0 >= m1) { rm = (c0 > 0.0f) - (c0 < 0.0f); cm = 0; }
        else          { rm = 0; cm = (c1 > 0.0f) - (c1 < 0.0f); }
        pr = min(max(pr + rm, 0), IMSZ - PSZ);
        pc = min(max(pc + cm, 0), IMSZ - PSZ);
        pos[b] = (pr << 8) | pc;

        // ---- coact: block reduce 120 symmetric pairs -> replica atomics ----
        float4* sv = (float4*)&sS[tid * 16];
        sv[0] = make_float4(st[0], st[1], st[2], st[3]);
        sv[1] = make_float4(st[4], st[5], st[6], st[7]);
        sv[2] = make_float4(st[8], st[9], st[10], st[11]);
        sv[3] = make_float4(st[12], st[13], st[14], 0.0f);
        __syncthreads();
        if (tid < NPAIR) {
            int i = 0, p = tid;
            while (p >= 15 - i) { p -= 15 - i; ++i; }
            const int j = i + p;
            float acc = 0.0f;
#pragma unroll 8
            for (int bb = 0; bb < 256; ++bb)
                acc = fmaf(sS[bb * 16 + i], sS[bb * 16 + j], acc);
            atomicAdd(&coact_out[(blockIdx.x & (NREP - 1)) * CSTR + tid], acc);
        }
    }
}

extern "C" void kernel_launch(void* const* d_in, const int* in_sizes, int n_in,
                              void* d_out, int out_size, void* d_ws, size_t ws_size,
                              hipStream_t stream) {
    const float* x     = (const float*)d_in[0];
    const float* Wi    = (const float*)d_in[1];
    const float* bi    = (const float*)d_in[2];
    const float* gamma = (const float*)d_in[3];
    const float* beta  = (const float*)d_in[4];
    const float* R     = (const float*)d_in[5];
    const float* rb    = (const float*)d_in[6];
    const float* mask  = (const float*)d_in[7];
    const float* Wc    = (const float*)d_in[8];
    const float* bc    = (const float*)d_in[9];
    const float* Wo    = (const float*)d_in[10];
    const float* bo    = (const float*)d_in[11];
    float* out = (float*)d_out;

    const int B = in_sizes[0] / (IMSZ * IMSZ);
    const float lamB = LAMF / (float)B;
    const int grid = B / 256;

    // workspace: state 15*B f32 | pos B i32 | coact 4 steps * NREP * CSTR f32
    float* wsf = (float*)d_ws;
    float* state = wsf;
    int* pos = (int*)(wsf + (size_t)15 * B);
    float* coact = wsf + (size_t)15 * B + (size_t)B;

    hipMemsetAsync(coact, 0, (size_t)4 * NREP * CSTR * sizeof(float), stream);

    step_spt<true, false><<<grid, 256, 0, stream>>>(
        x, Wi, bi, gamma, beta, R, rb, mask, Wc, bc, Wo, bo,
        state, pos, nullptr, coact + 0 * NREP * CSTR, nullptr, B, lamB);
    step_spt<false, false><<<grid, 256, 0, stream>>>(
        x, Wi, bi, gamma, beta, R, rb, mask, Wc, bc, Wo, bo,
        state, pos, coact + 0 * NREP * CSTR, coact + 1 * NREP * CSTR, nullptr, B, lamB);
    step_spt<false, false><<<grid, 256, 0, stream>>>(
        x, Wi, bi, gamma, beta, R, rb, mask, Wc, bc, Wo, bo,
        state, pos, coact + 1 * NREP * CSTR, coact + 2 * NREP * CSTR, nullptr, B, lamB);
    step_spt<false, false><<<grid, 256, 0, stream>>>(
        x, Wi, bi, gamma, beta, R, rb, mask, Wc, bc, Wo, bo,
        state, pos, coact + 2 * NREP * CSTR, coact + 3 * NREP * CSTR, nullptr, B, lamB);
    step_spt<false, true><<<grid, 256, 0, stream>>>(
        x, Wi, bi, gamma, beta, R, rb, mask, Wc, bc, Wo, bo,
        state, pos, coact + 3 * NREP * CSTR, nullptr, out, B, lamB);
}